// Round 1
// baseline (2462.894 us; speedup 1.0000x reference)
//
#include <hip/hip_runtime.h>
#include <stdint.h>
#include <stddef.h>

// ---------------------------------------------------------------------------
// TextRNN: embed -> BiLSTM(512 steps) -> linear -> softmax   (MI355X gfx950)
//
// K0: transpose/cast Wx,Wh (f32 [256][1024]) -> bf16 [1024][256]  (col-major)
// K1: zx[dir][t][col][b] (bf16) = (emb[tokens] @ Wx + b) via mfma 16x16x32 bf16
// K2 (R4 redesign): per dir, 4 batch-groups (16 rows) x 4 h-dim-groups
//     (64 dims). Sync group shrinks 16 -> 4 blocks (3 remote producers):
//     a block's A-rows are its OWN 16 batch rows, so only its row-group's
//     h is needed. Wh B-fragments live in VGPRs (128 regs/lane, no LDS in
//     the hot loop). Own-block h goes through LDS (never L3). Producer
//     stores are NOT drained; the next poll's vmcnt(0) drains them in
//     parallel with the poll-load RT (protocol makes buffer reuse safe
//     without the drain). Tagged-word scheme unchanged from R3.
// K3: logits = [h_f|h_b] @ W_out + b_out; softmax -> d_out (f32 64x10)
// ---------------------------------------------------------------------------

typedef __attribute__((ext_vector_type(8))) short   short8;
typedef __attribute__((ext_vector_type(4))) float   f32x4;
typedef __attribute__((ext_vector_type(4))) unsigned short ushort4v;
typedef __attribute__((ext_vector_type(4))) unsigned int   uint4v;

// ws byte offsets
#define ZX_OFF    ((size_t)0)                        // 2*512*1024*64 bf16 = 134217728 B
#define WXT_OFF   ((size_t)134217728)                // 2*1024*256 bf16    = 1048576 B
#define WHT_OFF   ((size_t)135266304)                // 2*1024*256 bf16    = 1048576 B
#define HBUF_OFF  ((size_t)136314880)                // 2 dir*4 rg*2 buf*16*256 u32 = 262144 B
#define WS_NEED   ((size_t)136577024)

__device__ __forceinline__ unsigned short f2bf(float f) {
  unsigned int u = __builtin_bit_cast(unsigned int, f);
  u += 0x7fffu + ((u >> 16) & 1u);            // RNE
  return (unsigned short)(u >> 16);
}
__device__ __forceinline__ float bf2f(unsigned short b) {
  unsigned int u = ((unsigned int)b) << 16;
  return __builtin_bit_cast(float, u);
}
__device__ __forceinline__ float sigf(float x) { return 1.0f / (1.0f + __expf(-x)); }
__device__ __forceinline__ float tanhf_(float x) {
  float t = __expf(-2.0f * fabsf(x));
  float r = (1.0f - t) / (1.0f + t);          // no inf/NaN for any x
  return copysignf(r, x);
}

// ---------------------------------------------------------------------------
// K0: W (f32 [256][1024]) -> Wt (bf16 [1024][256]).  z selects matrix.
__global__ __launch_bounds__(256) void k0_transpose(
    const float* __restrict__ wxf, const float* __restrict__ wxb,
    const float* __restrict__ whf, const float* __restrict__ whb,
    unsigned short* __restrict__ wxt, unsigned short* __restrict__ wht) {
  __shared__ float lds[32][33];
  int mat = blockIdx.z;
  const float* src = (mat == 0) ? wxf : (mat == 1) ? wxb : (mat == 2) ? whf : whb;
  unsigned short* dst = (mat == 0) ? wxt : (mat == 1) ? (wxt + 262144)
                      : (mat == 2) ? wht : (wht + 262144);
  int k0 = blockIdx.x * 32;
  int n0 = blockIdx.y * 32;
  int tx = threadIdx.x & 31, ty = threadIdx.x >> 5;   // ty 0..7
#pragma unroll
  for (int r = 0; r < 4; r++) {
    int k = ty + r * 8;
    lds[k][tx] = src[(size_t)(k0 + k) * 1024 + n0 + tx];
  }
  __syncthreads();
#pragma unroll
  for (int r = 0; r < 4; r++) {
    int n = ty + r * 8;
    dst[(size_t)(n0 + n) * 256 + k0 + tx] = f2bf(lds[tx][n]);
  }
}

// ---------------------------------------------------------------------------
// K1: zx[dir][t][col][b] = emb[tok[b][t_src]] @ Wx + bias   (bf16 out)
// grid (512 t, 16 coltiles, 2 dir), block 256 (4 waves). Tile: 64 b x 64 cols.
__global__ __launch_bounds__(256) void k1_zx(
    const int* __restrict__ tokens, const float* __restrict__ emb,
    const unsigned short* __restrict__ wxt,   // [2][1024][256] bf16
    const float* __restrict__ bf_, const float* __restrict__ bb_,
    unsigned short* __restrict__ zx) {        // [2][512][1024][64] bf16
  int t  = blockIdx.x;
  int ct = blockIdx.y;
  int d  = blockIdx.z;
  int tid = threadIdx.x;
  int w = tid >> 6, lane = tid & 63, q = lane >> 4, l16 = lane & 15;
  int t_src = d ? (511 - t) : t;
  int b_row = w * 16 + l16;
  int tok = tokens[b_row * 512 + t_src];
  const float* embrow = emb + (size_t)tok * 256;
  const unsigned short* wxd = wxt + (size_t)d * 262144;
  const float* bias = d ? bb_ : bf_;

  f32x4 acc[4];
#pragma unroll
  for (int cs = 0; cs < 4; cs++) acc[cs] = {0.f, 0.f, 0.f, 0.f};

#pragma unroll
  for (int kt = 0; kt < 8; kt++) {
    int kbase = kt * 32 + q * 8;
    f32x4 v0 = *(const f32x4*)(embrow + kbase);
    f32x4 v1 = *(const f32x4*)(embrow + kbase + 4);
    short8 afrag;
#pragma unroll
    for (int j = 0; j < 4; j++) {
      afrag[j]     = (short)f2bf(v0[j]);
      afrag[4 + j] = (short)f2bf(v1[j]);
    }
#pragma unroll
    for (int cs = 0; cs < 4; cs++) {
      int gcol = ct * 64 + cs * 16 + l16;
      short8 bfrag = *(const short8*)(wxd + (size_t)gcol * 256 + kbase);
      acc[cs] = __builtin_amdgcn_mfma_f32_16x16x32_bf16(afrag, bfrag, acc[cs], 0, 0, 0);
    }
  }
  // epilogue: +bias, cast bf16, store [t][col][b] (4 consecutive b per lane)
#pragma unroll
  for (int cs = 0; cs < 4; cs++) {
    int gcol = ct * 64 + cs * 16 + l16;
    float bv = bias[gcol];
    ushort4v st;
#pragma unroll
    for (int r = 0; r < 4; r++) st[r] = f2bf(acc[cs][r] + bv);
    size_t idx = ((size_t)(d * 512 + t) * 1024 + gcol) * 64 + (w * 16 + q * 4);
    *(ushort4v*)(zx + idx) = st;
  }
}

// ---------------------------------------------------------------------------
// K2: recurrence. 32 blocks (16/dir = 4 rg x 4 cg), 256 thr (4 waves).
// Block (d,rg,cg): batch rows rg*16..+16, gate cols {G*256 + cg*64 + j}.
// Wave w: h-dims w*16..+16 of this cg (cols gate-major: cs = gate) -> all
// 4 gates of a dim land in one lane's accumulators -> c-state in registers.
// hbuf layout: [d][rg][buf][row 16][dim 256] tagged u32 ((t<<16)|bf16).
__global__ __launch_bounds__(256, 1) void k2_rnn(
    const unsigned short* __restrict__ zx,    // [2][512][1024][64] bf16
    const unsigned short* __restrict__ wht,   // [2][1024][256] bf16
    unsigned int* __restrict__ hbufw) {       // [2][4][2][16][256] u32 tagged
  int bx = blockIdx.x;
  int d  = bx >> 4;
  int rg = (bx >> 2) & 3;
  int cg = bx & 3;
  int tid = threadIdx.x;
  int w = tid >> 6, lane = tid & 63, q = lane >> 4, l16 = lane & 15;

  // own h-dims, double-buffered; pad row to 72 shorts (144 B -> bank shift 4)
  __shared__ unsigned short hl[2][16][72];

  // Wh B-fragments resident in VGPRs (128 regs/lane): col = cs*256+cg*64+w*16+l16
  const unsigned short* whd = wht + (size_t)d * 262144;
  short8 bfr[4][8];
#pragma unroll
  for (int cs = 0; cs < 4; cs++) {
    const unsigned short* wp = whd + (size_t)(cs * 256 + cg * 64 + w * 16 + l16) * 256;
#pragma unroll
    for (int kt = 0; kt < 8; kt++)
      bfr[cs][kt] = *(const short8*)(wp + kt * 32 + q * 8);
  }

  for (int i = tid; i < 2 * 16 * 72; i += 256) (&hl[0][0][0])[i] = 0;
  __syncthreads();

  float cst[4] = {0.f, 0.f, 0.f, 0.f};        // c for (row=q*4+r, dim=w*16+l16)
  unsigned int* hb = hbufw + (size_t)(d * 4 + rg) * 8192;   // words per (d,rg)
  int rowoff = l16 * 256 + q * 8;                           // consumer base
  int srow   = (q * 4) * 256 + cg * 64 + w * 16 + l16;      // producer base

  for (int t = 0; t < 512; t++) {
    // prefetch zx for this step (in flight during the poll; vmcnt(0) covers it)
    ushort4v zv[4];
    size_t zbase = (size_t)(d * 512 + t) * 65536;
#pragma unroll
    for (int cs = 0; cs < 4; cs++) {
      int gcol = cs * 256 + cg * 64 + w * 16 + l16;
      zv[cs] = *(const ushort4v*)(zx + zbase + (size_t)gcol * 64 + (rg * 16 + q * 4));
    }
    // own h A-fragments from LDS (written end of prev step, behind barrier)
    short8 ownA[2];
#pragma unroll
    for (int i = 0; i < 2; i++)
      ownA[i] = *(const short8*)(&hl[t & 1][l16][i * 32 + q * 8]);

    // poll-load h A-fragments (tagged words) until the 3 REMOTE producers'
    // tags == t. First round's vmcnt(0) also drains our un-drained stores
    // from the previous step (overlapped with the load RT).
    const unsigned int* hp = hb + (t & 1) * 4096 + rowoff;
    unsigned int tg = (unsigned int)t << 16;
    uint4v hA[8], hB[8];
    while (true) {
      asm volatile(
          "global_load_dwordx4 %[a0], %[p], off sc1\n\t"
          "global_load_dwordx4 %[b0], %[p], off offset:16 sc1\n\t"
          "global_load_dwordx4 %[a1], %[p], off offset:128 sc1\n\t"
          "global_load_dwordx4 %[b1], %[p], off offset:144 sc1\n\t"
          "global_load_dwordx4 %[a2], %[p], off offset:256 sc1\n\t"
          "global_load_dwordx4 %[b2], %[p], off offset:272 sc1\n\t"
          "global_load_dwordx4 %[a3], %[p], off offset:384 sc1\n\t"
          "global_load_dwordx4 %[b3], %[p], off offset:400 sc1\n\t"
          "global_load_dwordx4 %[a4], %[p], off offset:512 sc1\n\t"
          "global_load_dwordx4 %[b4], %[p], off offset:528 sc1\n\t"
          "global_load_dwordx4 %[a5], %[p], off offset:640 sc1\n\t"
          "global_load_dwordx4 %[b5], %[p], off offset:656 sc1\n\t"
          "global_load_dwordx4 %[a6], %[p], off offset:768 sc1\n\t"
          "global_load_dwordx4 %[b6], %[p], off offset:784 sc1\n\t"
          "global_load_dwordx4 %[a7], %[p], off offset:896 sc1\n\t"
          "global_load_dwordx4 %[b7], %[p], off offset:912 sc1\n\t"
          "s_waitcnt vmcnt(0)"
          : [a0] "=&v"(hA[0]), [b0] "=&v"(hB[0]), [a1] "=&v"(hA[1]), [b1] "=&v"(hB[1]),
            [a2] "=&v"(hA[2]), [b2] "=&v"(hB[2]), [a3] "=&v"(hA[3]), [b3] "=&v"(hB[3]),
            [a4] "=&v"(hA[4]), [b4] "=&v"(hB[4]), [a5] "=&v"(hA[5]), [b5] "=&v"(hB[5]),
            [a6] "=&v"(hA[6]), [b6] "=&v"(hB[6]), [a7] "=&v"(hA[7]), [b7] "=&v"(hB[7])
          : [p] "v"(hp)
          : "memory");
      // tag per 16B chunk; skip the block's OWN chunks (kt>>1 == cg) — those
      // come from LDS and their L3 copy may legitimately still be in flight.
      unsigned int bad = 0;
#pragma unroll
      for (int kt = 0; kt < 8; kt++)
        if ((kt >> 1) != cg)
          bad |= (hA[kt][0] ^ tg) | (hB[kt][0] ^ tg) |
                 (hA[kt][1] ^ tg) | (hB[kt][1] ^ tg) |
                 (hA[kt][2] ^ tg) | (hB[kt][2] ^ tg) |
                 (hA[kt][3] ^ tg) | (hB[kt][3] ^ tg);
      if (__all((bad & 0xffff0000u) == 0)) break;
    }

    f32x4 acc[4];
#pragma unroll
    for (int cs = 0; cs < 4; cs++)
#pragma unroll
      for (int r = 0; r < 4; r++) acc[cs][r] = bf2f(zv[cs][r]);

#pragma unroll
    for (int kt = 0; kt < 8; kt++) {
      short8 afrag;
      if ((kt >> 1) == cg) {
        afrag = ownA[kt & 1];
      } else {
        // pack 8 tagged words -> 8 bf16 (v_perm_b32, low halves)
        uint4v pk;
        pk[0] = __builtin_amdgcn_perm(hA[kt][1], hA[kt][0], 0x05040100u);
        pk[1] = __builtin_amdgcn_perm(hA[kt][3], hA[kt][2], 0x05040100u);
        pk[2] = __builtin_amdgcn_perm(hB[kt][1], hB[kt][0], 0x05040100u);
        pk[3] = __builtin_amdgcn_perm(hB[kt][3], hB[kt][2], 0x05040100u);
        afrag = __builtin_bit_cast(short8, pk);
      }
#pragma unroll
      for (int cs = 0; cs < 4; cs++)
        acc[cs] = __builtin_amdgcn_mfma_f32_16x16x32_bf16(afrag, bfr[cs][kt], acc[cs], 0, 0, 0);
    }

    unsigned int* hwn = hb + ((t + 1) & 1) * 4096 + srow;
    unsigned int wtag = ((unsigned int)(t + 1)) << 16;
    unsigned int sw[4];
#pragma unroll
    for (int r = 0; r < 4; r++) {
      float iv = sigf(acc[0][r]);
      float fv = sigf(acc[1][r]);
      float gv = tanhf_(acc[2][r]);
      float ov = sigf(acc[3][r]);
      cst[r] = fv * cst[r] + iv * gv;
      float hv = ov * tanhf_(cst[r]);
      sw[r] = wtag | (unsigned int)f2bf(hv);
      hl[(t + 1) & 1][q * 4 + r][w * 16 + l16] = (unsigned short)(sw[r] & 0xffffu);
    }
    // tagged h stores for the 3 remote partners (rows at word-stride 256).
    // NO drain: next poll's vmcnt(0) drains them, overlapped with its RT.
    asm volatile(
        "global_store_dword %[p], %[v0], off sc1\n\t"
        "global_store_dword %[p], %[v1], off offset:1024 sc1\n\t"
        "global_store_dword %[p], %[v2], off offset:2048 sc1\n\t"
        "global_store_dword %[p], %[v3], off offset:3072 sc1"
        :: [p] "v"(hwn), [v0] "v"(sw[0]), [v1] "v"(sw[1]),
           [v2] "v"(sw[2]), [v3] "v"(sw[3])
        : "memory");
    __syncthreads();   // publishes hl[(t+1)&1] to the block's other waves
  }
}

// ---------------------------------------------------------------------------
// K3: logits + softmax. 64 blocks (one per batch) x 64 threads (one wave).
// Final h_512 sits in buf0 of each (dir, rg) (tagged words; low16 = bf16).
__global__ __launch_bounds__(64) void k3_out(
    const unsigned int* __restrict__ hbufw,
    const float* __restrict__ wout, const float* __restrict__ bout,
    float* __restrict__ out) {
  int b = blockIdx.x, tid = threadIdx.x;
  int rg = b >> 4, r = b & 15;
  const unsigned int* hf  = hbufw + (size_t)rg * 8192 + r * 256;           // dir0 buf0
  const unsigned int* hbk = hbufw + 32768 + (size_t)rg * 8192 + r * 256;   // dir1 buf0
  float p[10];
#pragma unroll
  for (int l = 0; l < 10; l++) p[l] = 0.f;
  for (int k = tid; k < 512; k += 64) {
    unsigned int wd = (k < 256) ? hf[k] : hbk[k - 256];
    float f = bf2f((unsigned short)(wd & 0xffffu));
    const float* wr = wout + k * 10;
#pragma unroll
    for (int l = 0; l < 10; l++) p[l] += f * wr[l];
  }
#pragma unroll
  for (int off = 32; off; off >>= 1)
#pragma unroll
    for (int l = 0; l < 10; l++) p[l] += __shfl_down(p[l], off);
  if (tid == 0) {
    float lg[10], m = -1e30f;
#pragma unroll
    for (int l = 0; l < 10; l++) { lg[l] = p[l] + bout[l]; m = fmaxf(m, lg[l]); }
    float sum = 0.f;
#pragma unroll
    for (int l = 0; l < 10; l++) { lg[l] = __expf(lg[l] - m); sum += lg[l]; }
    float inv = 1.0f / sum;
#pragma unroll
    for (int l = 0; l < 10; l++) out[b * 10 + l] = lg[l] * inv;
  }
}

// ---------------------------------------------------------------------------
extern "C" void kernel_launch(void* const* d_in, const int* in_sizes, int n_in,
                              void* d_out, int out_size, void* d_ws, size_t ws_size,
                              hipStream_t stream) {
  const int*   tokens = (const int*)d_in[0];
  const float* emb    = (const float*)d_in[1];
  const float* wxf    = (const float*)d_in[2];
  const float* whf    = (const float*)d_in[3];
  const float* bf_    = (const float*)d_in[4];
  const float* wxb    = (const float*)d_in[5];
  const float* whb    = (const float*)d_in[6];
  const float* bb_    = (const float*)d_in[7];
  const float* wout   = (const float*)d_in[8];
  const float* bout   = (const float*)d_in[9];
  float* out = (float*)d_out;

  char* ws = (char*)d_ws;
  unsigned short* zx    = (unsigned short*)(ws + ZX_OFF);
  unsigned short* wxt   = (unsigned short*)(ws + WXT_OFF);
  unsigned short* wht   = (unsigned short*)(ws + WHT_OFF);
  unsigned int*   hbufw = (unsigned int*)(ws + HBUF_OFF);
  (void)ws_size; (void)in_sizes; (void)n_in; (void)out_size;   // needs WS_NEED bytes

  // zero h0 (tag 0 == step 0) in all [d][rg] buffers
  hipMemsetAsync(ws + HBUF_OFF, 0, 262144, stream);

  k0_transpose<<<dim3(8, 32, 4), 256, 0, stream>>>(wxf, wxb, whf, whb, wxt, wht);
  k1_zx<<<dim3(512, 16, 2), 256, 0, stream>>>(tokens, emb, wxt, bf_, bb_, zx);
  k2_rnn<<<32, 256, 0, stream>>>(zx, wht, hbufw);
  k3_out<<<64, 64, 0, stream>>>(hbufw, wout, bout, out);
}

// Round 2
// 1941.494 us; speedup vs baseline: 1.2686x; 1.2686x over previous
//
#include <hip/hip_runtime.h>
#include <stdint.h>
#include <stddef.h>

// ---------------------------------------------------------------------------
// TextRNN: embed -> BiLSTM(512 steps) -> linear -> softmax   (MI355X gfx950)
//
// R5 structure:
// K0 : transpose/cast Wx,Wh (f32 [256][1024]) -> bf16 [1024][256]
// K0b: cast emb table f32 -> bf16 (one-time, enables fused zx)
// K2 : fused zx + recurrence. 32 blocks (2 dir x 4 rg x 4 cg), 256 thr.
//      Per step: (a) compute zx tile in-block via MFMA from bf16 emb gather
//      + LDS-resident Wx slice (overlaps partners' store propagation);
//      (b) SLIM poll: each wave polls only its 4 rows x 3 remote producers
//      (12 KB/block/round vs R4's 64 KB) -- the R2..R4 rounds' fat
//      redundant sc1 loads were congesting the TCC/MALL path the
//      producers' stores propagate through; (c) deposit packed bf16 into a
//      shared LDS h-tile ([kchunk][row][8] interleave, conflict-free
//      ds_read_b128), one barrier, MFMA vs VGPR-resident Wh.
//      Tagged-word sc1 exchange protocol unchanged (harness-proven).
// K3 : logits = [h_f|h_b] @ W_out + b_out; softmax -> d_out (f32 64x10)
// ---------------------------------------------------------------------------

typedef __attribute__((ext_vector_type(8))) short   short8;
typedef __attribute__((ext_vector_type(4))) float   f32x4;
typedef __attribute__((ext_vector_type(4))) unsigned short ushort4v;
typedef __attribute__((ext_vector_type(4))) unsigned int   uint4v;
typedef __attribute__((ext_vector_type(2))) unsigned int   uint2v;

// ws byte offsets
#define EMB16_OFF ((size_t)0)            // 50000*256 bf16 = 25,600,000 B
#define WXT_OFF   ((size_t)25600000)     // 2*1024*256 bf16 = 1,048,576 B
#define WHT_OFF   ((size_t)26648576)     // 2*1024*256 bf16 = 1,048,576 B
#define HBUF_OFF  ((size_t)27697152)     // 2 dir*4 rg*2 buf*16*256 u32 = 262,144 B
#define WS_NEED   ((size_t)27959296)

__device__ __forceinline__ unsigned short f2bf(float f) {
  unsigned int u = __builtin_bit_cast(unsigned int, f);
  u += 0x7fffu + ((u >> 16) & 1u);            // RNE
  return (unsigned short)(u >> 16);
}
__device__ __forceinline__ float bf2f(unsigned short b) {
  unsigned int u = ((unsigned int)b) << 16;
  return __builtin_bit_cast(float, u);
}
__device__ __forceinline__ float sigf(float x) { return 1.0f / (1.0f + __expf(-x)); }
__device__ __forceinline__ float tanhf_(float x) {
  float t = __expf(-2.0f * fabsf(x));
  float r = (1.0f - t) / (1.0f + t);          // no inf/NaN for any x
  return copysignf(r, x);
}

// ---------------------------------------------------------------------------
// K0: W (f32 [256][1024]) -> Wt (bf16 [1024][256]).  z selects matrix.
__global__ __launch_bounds__(256) void k0_transpose(
    const float* __restrict__ wxf, const float* __restrict__ wxb,
    const float* __restrict__ whf, const float* __restrict__ whb,
    unsigned short* __restrict__ wxt, unsigned short* __restrict__ wht) {
  __shared__ float lds[32][33];
  int mat = blockIdx.z;
  const float* src = (mat == 0) ? wxf : (mat == 1) ? wxb : (mat == 2) ? whf : whb;
  unsigned short* dst = (mat == 0) ? wxt : (mat == 1) ? (wxt + 262144)
                      : (mat == 2) ? wht : (wht + 262144);
  int k0 = blockIdx.x * 32;
  int n0 = blockIdx.y * 32;
  int tx = threadIdx.x & 31, ty = threadIdx.x >> 5;   // ty 0..7
#pragma unroll
  for (int r = 0; r < 4; r++) {
    int k = ty + r * 8;
    lds[k][tx] = src[(size_t)(k0 + k) * 1024 + n0 + tx];
  }
  __syncthreads();
#pragma unroll
  for (int r = 0; r < 4; r++) {
    int n = ty + r * 8;
    dst[(size_t)(n0 + n) * 256 + k0 + tx] = f2bf(lds[tx][n]);
  }
}

// ---------------------------------------------------------------------------
// K0b: emb table f32 -> bf16.  50000*256 = 12.8M elems, 8/thread, 6250 blocks.
__global__ __launch_bounds__(256) void k0b_embcast(
    const float* __restrict__ emb, unsigned short* __restrict__ embbf) {
  size_t i = ((size_t)blockIdx.x * 256 + threadIdx.x) * 8;
  f32x4 v0 = *(const f32x4*)(emb + i);
  f32x4 v1 = *(const f32x4*)(emb + i + 4);
  short8 st;
#pragma unroll
  for (int j = 0; j < 4; j++) {
    st[j]     = (short)f2bf(v0[j]);
    st[4 + j] = (short)f2bf(v1[j]);
  }
  *(short8*)(embbf + i) = st;
}

// ---------------------------------------------------------------------------
// K2: fused zx + recurrence. 32 blocks (2 d x 4 rg x 4 cg), 256 thr (4 waves).
// Block (d,rg,cg): batch rows rg*16..+16, h-dims cg*64..+64 (all 4 gates).
// Wave w: dims w*16..+16 of this cg; lane (q,l16): rows q*4..+4, dim w*16+l16;
// gate-major accumulators (cs = gate) -> c-state in registers.
// hbuf: [d][rg][buf][row 16][dim 256] tagged u32 ((t<<16)|bf16).
// LDS h tile: hl[buf][ch=dim>>3][row][dim&7] bf16 (conflict-free b128 reads:
// A-frag (row=l16, k=kt*32+q*8..) = hl[buf][kt*4+q][l16][0..7]).
__global__ __launch_bounds__(256, 1) void k2_rnn(
    const int* __restrict__ tokens, const unsigned short* __restrict__ embbf,
    const unsigned short* __restrict__ wxt,   // [2][1024][256] bf16
    const unsigned short* __restrict__ wht,   // [2][1024][256] bf16
    const float* __restrict__ bf_, const float* __restrict__ bb_,
    unsigned int* __restrict__ hbufw) {       // [2][4][2][16][256] u32 tagged
  int bx = blockIdx.x;
  int d  = bx >> 4;
  int rg = (bx >> 2) & 3;
  int cg = bx & 3;
  int tid = threadIdx.x;
  int w = tid >> 6, lane = tid & 63, q = lane >> 4, l16 = lane & 15;

  __shared__ unsigned short wx2[32][256][8];    // Wx slice, interleaved: 131072 B
  __shared__ unsigned short hl[2][32][16][8];   // h tiles, interleaved:   16384 B

  // ---- preload Wx slice (block cols: gate*256 + cg*64 + dl) into wx2 ----
  const unsigned short* wxd = wxt + (size_t)d * 262144;
  for (int it = 0; it < 32; ++it) {
    int idx = it * 256 + tid;                 // 8192 16B-chunks
    int cl = idx & 255, ch = idx >> 8;        // cl = cs*64+dl, ch = kt*4+q
    int gcol = (cl >> 6) * 256 + cg * 64 + (cl & 63);
    *(short8*)(&wx2[ch][cl][0]) = *(const short8*)(wxd + (size_t)gcol * 256 + ch * 8);
  }

  // ---- Wh B-fragments resident in VGPRs (128 regs/lane) ----
  const unsigned short* whd = wht + (size_t)d * 262144;
  short8 bfr[4][8];
#pragma unroll
  for (int cs = 0; cs < 4; cs++) {
    const unsigned short* wp = whd + (size_t)(cs * 256 + cg * 64 + w * 16 + l16) * 256;
#pragma unroll
    for (int kt = 0; kt < 8; kt++)
      bfr[cs][kt] = *(const short8*)(wp + kt * 32 + q * 8);
  }

  // zero h LDS tiles (h0 = 0)
  {
    unsigned int* hlw = (unsigned int*)&hl[0][0][0][0];
    for (int i = tid; i < 4096; i += 256) hlw[i] = 0;
  }
  __syncthreads();

  const float* bias = d ? bb_ : bf_;
  float bv[4];
#pragma unroll
  for (int cs = 0; cs < 4; cs++) bv[cs] = bias[cs * 256 + cg * 64 + w * 16 + l16];

  float cst[4] = {0.f, 0.f, 0.f, 0.f};        // c for (row=q*4+r, dim=w*16+l16)
  unsigned int* hb = hbufw + (size_t)(d * 4 + rg) * 8192;   // words per (d,rg)
  int prow = w * 4 + (lane >> 4);             // this wave's poll rows: 4w..4w+3
  int ps   = lane & 15;                        // dim quad within 64
  int rcg0 = (cg + 1) & 3, rcg1 = (cg + 2) & 3, rcg2 = (cg + 3) & 3;
  int pbase = prow * 256 + ps * 4;            // words
  int srow  = (q * 4) * 256 + cg * 64 + w * 16 + l16;       // producer base
  const int* tokrow = tokens + (rg * 16 + l16) * 512;

  for (int t = 0; t < 512; ++t) {
    int buf = t & 1;
    int t_src = d ? (511 - t) : t;

    // ---- zx tile (does not depend on h; overlaps partners' store drain) ----
    int tok = tokrow[t_src];
    const unsigned short* erow = embbf + (size_t)tok * 256 + q * 8;
    short8 ea[8];
#pragma unroll
    for (int kt = 0; kt < 8; ++kt) ea[kt] = *(const short8*)(erow + kt * 32);

    f32x4 acc[4];
#pragma unroll
    for (int cs = 0; cs < 4; ++cs) acc[cs] = {0.f, 0.f, 0.f, 0.f};
#pragma unroll
    for (int kt = 0; kt < 8; ++kt) {
#pragma unroll
      for (int cs = 0; cs < 4; ++cs) {
        short8 xb = *(const short8*)(&wx2[kt * 4 + q][cs * 64 + w * 16 + l16][0]);
        acc[cs] = __builtin_amdgcn_mfma_f32_16x16x32_bf16(ea[kt], xb, acc[cs], 0, 0, 0);
      }
    }

    // ---- slim poll: 3 remote producers x this wave's 4 rows (12 KB/blk/rnd).
    // First round's vmcnt(0) also drains our prev-step stores (overlapped).
    const unsigned int* q0 = hb + buf * 4096 + pbase + rcg0 * 64;
    const unsigned int* q1 = hb + buf * 4096 + pbase + rcg1 * 64;
    const unsigned int* q2 = hb + buf * 4096 + pbase + rcg2 * 64;
    unsigned int tg = (unsigned int)t << 16;
    uint4v r0, r1, r2;
    while (true) {
      asm volatile(
          "global_load_dwordx4 %[r0], %[p0], off sc1\n\t"
          "global_load_dwordx4 %[r1], %[p1], off sc1\n\t"
          "global_load_dwordx4 %[r2], %[p2], off sc1\n\t"
          "s_waitcnt vmcnt(0)"
          : [r0] "=&v"(r0), [r1] "=&v"(r1), [r2] "=&v"(r2)
          : [p0] "v"(q0), [p1] "v"(q1), [p2] "v"(q2)
          : "memory");
      unsigned int bad = (r0[0] ^ tg) | (r0[1] ^ tg) | (r0[2] ^ tg) | (r0[3] ^ tg)
                       | (r1[0] ^ tg) | (r1[1] ^ tg) | (r1[2] ^ tg) | (r1[3] ^ tg)
                       | (r2[0] ^ tg) | (r2[1] ^ tg) | (r2[2] ^ tg) | (r2[3] ^ tg);
      if (__all((bad & 0xffff0000u) == 0)) break;
    }
    // deposit packed bf16 into hl[buf] (remote dims; own dims already there)
    {
      int e4 = (ps & 1) * 4, ch2 = ps >> 1;
      uint2v w0, w1, w2;
      w0[0] = __builtin_amdgcn_perm(r0[1], r0[0], 0x05040100u);
      w0[1] = __builtin_amdgcn_perm(r0[3], r0[2], 0x05040100u);
      w1[0] = __builtin_amdgcn_perm(r1[1], r1[0], 0x05040100u);
      w1[1] = __builtin_amdgcn_perm(r1[3], r1[2], 0x05040100u);
      w2[0] = __builtin_amdgcn_perm(r2[1], r2[0], 0x05040100u);
      w2[1] = __builtin_amdgcn_perm(r2[3], r2[2], 0x05040100u);
      *(uint2v*)(&hl[buf][rcg0 * 8 + ch2][prow][e4]) = w0;
      *(uint2v*)(&hl[buf][rcg1 * 8 + ch2][prow][e4]) = w1;
      *(uint2v*)(&hl[buf][rcg2 * 8 + ch2][prow][e4]) = w2;
    }
    __syncthreads();   // hl[buf] complete; also publishes prev epilogue writes

    // ---- h GEMM: A from LDS tile (conflict-free b128), B from VGPRs ----
#pragma unroll
    for (int kt = 0; kt < 8; ++kt) {
      short8 ha = *(const short8*)(&hl[buf][kt * 4 + q][l16][0]);
#pragma unroll
      for (int cs = 0; cs < 4; ++cs)
        acc[cs] = __builtin_amdgcn_mfma_f32_16x16x32_bf16(ha, bfr[cs][kt], acc[cs], 0, 0, 0);
    }

    // ---- epilogue: gates, c/h update, LDS own-dims, tagged global stores ----
    unsigned int* hwn = hb + ((buf ^ 1) * 4096) + srow;
    unsigned int wtag = ((unsigned int)(t + 1)) << 16;
    int dim = cg * 64 + w * 16 + l16;
    int chO = dim >> 3, eO = dim & 7;
    unsigned int sw[4];
#pragma unroll
    for (int r = 0; r < 4; ++r) {
      float iv = sigf(acc[0][r] + bv[0]);
      float fv = sigf(acc[1][r] + bv[1]);
      float gv = tanhf_(acc[2][r] + bv[2]);
      float ov = sigf(acc[3][r] + bv[3]);
      cst[r] = fv * cst[r] + iv * gv;
      float hv = ov * tanhf_(cst[r]);
      unsigned short h16 = f2bf(hv);
      sw[r] = wtag | (unsigned int)h16;
      hl[buf ^ 1][chO][q * 4 + r][eO] = h16;
    }
    // tagged h stores for the 3 remote partners; NO drain (next poll's
    // vmcnt(0) drains them, overlapped with its RT).
    asm volatile(
        "global_store_dword %[p], %[v0], off sc1\n\t"
        "global_store_dword %[p], %[v1], off offset:1024 sc1\n\t"
        "global_store_dword %[p], %[v2], off offset:2048 sc1\n\t"
        "global_store_dword %[p], %[v3], off offset:3072 sc1"
        :: [p] "v"(hwn), [v0] "v"(sw[0]), [v1] "v"(sw[1]),
           [v2] "v"(sw[2]), [v3] "v"(sw[3])
        : "memory");
  }
}

// ---------------------------------------------------------------------------
// K3: logits + softmax. 64 blocks (one per batch) x 64 threads (one wave).
// Final h_512 sits in buf0 of each (dir, rg) (tagged words; low16 = bf16).
__global__ __launch_bounds__(64) void k3_out(
    const unsigned int* __restrict__ hbufw,
    const float* __restrict__ wout, const float* __restrict__ bout,
    float* __restrict__ out) {
  int b = blockIdx.x, tid = threadIdx.x;
  int rg = b >> 4, r = b & 15;
  const unsigned int* hf  = hbufw + (size_t)rg * 8192 + r * 256;           // dir0 buf0
  const unsigned int* hbk = hbufw + 32768 + (size_t)rg * 8192 + r * 256;   // dir1 buf0
  float p[10];
#pragma unroll
  for (int l = 0; l < 10; l++) p[l] = 0.f;
  for (int k = tid; k < 512; k += 64) {
    unsigned int wd = (k < 256) ? hf[k] : hbk[k - 256];
    float f = bf2f((unsigned short)(wd & 0xffffu));
    const float* wr = wout + k * 10;
#pragma unroll
    for (int l = 0; l < 10; l++) p[l] += f * wr[l];
  }
#pragma unroll
  for (int off = 32; off; off >>= 1)
#pragma unroll
    for (int l = 0; l < 10; l++) p[l] += __shfl_down(p[l], off);
  if (tid == 0) {
    float lg[10], m = -1e30f;
#pragma unroll
    for (int l = 0; l < 10; l++) { lg[l] = p[l] + bout[l]; m = fmaxf(m, lg[l]); }
    float sum = 0.f;
#pragma unroll
    for (int l = 0; l < 10; l++) { lg[l] = __expf(lg[l] - m); sum += lg[l]; }
    float inv = 1.0f / sum;
#pragma unroll
    for (int l = 0; l < 10; l++) out[b * 10 + l] = lg[l] * inv;
  }
}

// ---------------------------------------------------------------------------
extern "C" void kernel_launch(void* const* d_in, const int* in_sizes, int n_in,
                              void* d_out, int out_size, void* d_ws, size_t ws_size,
                              hipStream_t stream) {
  const int*   tokens = (const int*)d_in[0];
  const float* emb    = (const float*)d_in[1];
  const float* wxf    = (const float*)d_in[2];
  const float* whf    = (const float*)d_in[3];
  const float* bf_    = (const float*)d_in[4];
  const float* wxb    = (const float*)d_in[5];
  const float* whb    = (const float*)d_in[6];
  const float* bb_    = (const float*)d_in[7];
  const float* wout   = (const float*)d_in[8];
  const float* bout   = (const float*)d_in[9];
  float* out = (float*)d_out;

  char* ws = (char*)d_ws;
  unsigned short* embbf = (unsigned short*)(ws + EMB16_OFF);
  unsigned short* wxt   = (unsigned short*)(ws + WXT_OFF);
  unsigned short* wht   = (unsigned short*)(ws + WHT_OFF);
  unsigned int*   hbufw = (unsigned int*)(ws + HBUF_OFF);
  (void)ws_size; (void)in_sizes; (void)n_in; (void)out_size;   // needs WS_NEED bytes

  // zero h0 (tag 0 == step 0) in all [d][rg] buffers
  hipMemsetAsync(ws + HBUF_OFF, 0, 262144, stream);

  k0_transpose<<<dim3(8, 32, 4), 256, 0, stream>>>(wxf, wxb, whf, whb, wxt, wht);
  k0b_embcast<<<6250, 256, 0, stream>>>(emb, embbf);
  k2_rnn<<<32, 256, 0, stream>>>(tokens, embbf, wxt, wht, bf_, bb_, hbufw);
  k3_out<<<64, 64, 0, stream>>>(hbufw, wout, bout, out);
}

// Round 4
// 1419.841 us; speedup vs baseline: 1.7346x; 1.3674x over previous
//
#include <hip/hip_runtime.h>
#include <stdint.h>
#include <stddef.h>

// ---------------------------------------------------------------------------
// TextRNN: embed -> BiLSTM(512 steps) -> linear -> softmax   (MI355X gfx950)
//
// R7 structure (delta vs R6):
// * NO handshake / placement sensing. Producers DUAL-PUBLISH each step's
//   tagged h words: sc0 -> primary buffer (intra-XCD L2, fast when the
//   group's 4 blocks share an XCD) AND sc1 -> mirror buffer (MALL,
//   R5-proven, correct under ANY placement).
// * Consumers adaptively poll: sc0 primary for up to `limit` rounds
//   (limit starts 16, halves on each fallback -> converges to pure-sc1
//   mode if placement is bad), then sc1 mirror (always written ->
//   guaranteed progress; hang-proof by construction).
// * emb row for step t+1 prefetched right after the poll (hides HBM
//   gather latency under h-GEMM + epilogue).
// K0 : transpose/cast Wx,Wh (f32 [256][1024]) -> bf16 [1024][256]
// K0b: cast emb table f32 -> bf16
// K2 : fused zx + recurrence (32 blocks = 8 groups x 4 cg, 256 thr)
// K3 : logits + softmax (reads sc1 mirror)
// ---------------------------------------------------------------------------

typedef __attribute__((ext_vector_type(8))) short   short8;
typedef __attribute__((ext_vector_type(4))) float   f32x4;
typedef __attribute__((ext_vector_type(4))) unsigned short ushort4v;
typedef __attribute__((ext_vector_type(4))) unsigned int   uint4v;
typedef __attribute__((ext_vector_type(2))) unsigned int   uint2v;

// ws byte offsets
#define EMB16_OFF ((size_t)0)            // 50000*256 bf16 = 25,600,000 B
#define WXT_OFF   ((size_t)25600000)     // 2*1024*256 bf16 = 1,048,576 B
#define WHT_OFF   ((size_t)26648576)     // 2*1024*256 bf16 = 1,048,576 B
#define HBUF_OFF  ((size_t)27697152)     // primary 262,144 B + mirror 262,144 B
#define WS_NEED   ((size_t)28221440)

__device__ __forceinline__ unsigned short f2bf(float f) {
  unsigned int u = __builtin_bit_cast(unsigned int, f);
  u += 0x7fffu + ((u >> 16) & 1u);            // RNE
  return (unsigned short)(u >> 16);
}
__device__ __forceinline__ float bf2f(unsigned short b) {
  unsigned int u = ((unsigned int)b) << 16;
  return __builtin_bit_cast(float, u);
}
__device__ __forceinline__ float sigf(float x) { return 1.0f / (1.0f + __expf(-x)); }
__device__ __forceinline__ float tanhf_(float x) {
  float t = __expf(-2.0f * fabsf(x));
  float r = (1.0f - t) / (1.0f + t);          // no inf/NaN for any x
  return copysignf(r, x);
}

// ---------------------------------------------------------------------------
// K0: W (f32 [256][1024]) -> Wt (bf16 [1024][256]).  z selects matrix.
__global__ __launch_bounds__(256) void k0_transpose(
    const float* __restrict__ wxf, const float* __restrict__ wxb,
    const float* __restrict__ whf, const float* __restrict__ whb,
    unsigned short* __restrict__ wxt, unsigned short* __restrict__ wht) {
  __shared__ float lds[32][33];
  int mat = blockIdx.z;
  const float* src = (mat == 0) ? wxf : (mat == 1) ? wxb : (mat == 2) ? whf : whb;
  unsigned short* dst = (mat == 0) ? wxt : (mat == 1) ? (wxt + 262144)
                      : (mat == 2) ? wht : (wht + 262144);
  int k0 = blockIdx.x * 32;
  int n0 = blockIdx.y * 32;
  int tx = threadIdx.x & 31, ty = threadIdx.x >> 5;   // ty 0..7
#pragma unroll
  for (int r = 0; r < 4; r++) {
    int k = ty + r * 8;
    lds[k][tx] = src[(size_t)(k0 + k) * 1024 + n0 + tx];
  }
  __syncthreads();
#pragma unroll
  for (int r = 0; r < 4; r++) {
    int n = ty + r * 8;
    dst[(size_t)(n0 + n) * 256 + k0 + tx] = f2bf(lds[tx][n]);
  }
}

// ---------------------------------------------------------------------------
// K0b: emb table f32 -> bf16.  50000*256 = 12.8M elems, 8/thread, 6250 blocks.
__global__ __launch_bounds__(256) void k0b_embcast(
    const float* __restrict__ emb, unsigned short* __restrict__ embbf) {
  size_t i = ((size_t)blockIdx.x * 256 + threadIdx.x) * 8;
  f32x4 v0 = *(const f32x4*)(emb + i);
  f32x4 v1 = *(const f32x4*)(emb + i + 4);
  short8 st;
#pragma unroll
  for (int j = 0; j < 4; j++) {
    st[j]     = (short)f2bf(v0[j]);
    st[4 + j] = (short)f2bf(v1[j]);
  }
  *(short8*)(embbf + i) = st;
}

// ---------------------------------------------------------------------------
// K2: fused zx + recurrence. 32 blocks, 256 thr (4 waves).
// Group gid = bid&7 -> (d = gid>>2, rg = gid&3); member cg = bid>>3.
// (Under round-robin dispatch the 4 members of a group land on one XCD;
//  this is a SPEED heuristic only — correctness never depends on it.)
// Block (d,rg,cg): batch rows rg*16..+16, h-dims cg*64..+64 (all 4 gates).
// Wave w: dims w*16..+16; lane (q,l16): rows q*4..+4, dim w*16+l16;
// gate-major accumulators (cs = gate) -> c-state in registers.
// hbuf primary: [gid][buf][row 16][dim 256] tagged u32 ((t<<16)|bf16), sc0.
// hbuf mirror : same layout at +65536 words, sc1.
__global__ __launch_bounds__(256, 1) void k2_rnn(
    const int* __restrict__ tokens, const unsigned short* __restrict__ embbf,
    const unsigned short* __restrict__ wxt,   // [2][1024][256] bf16
    const unsigned short* __restrict__ wht,   // [2][1024][256] bf16
    const float* __restrict__ bf_, const float* __restrict__ bb_,
    unsigned int* __restrict__ hbufw) {
  int bx = blockIdx.x;
  int gid = bx & 7;
  int cg  = bx >> 3;
  int d   = gid >> 2;
  int rg  = gid & 3;
  int tid = threadIdx.x;
  int w = tid >> 6, lane = tid & 63, q = lane >> 4, l16 = lane & 15;

  __shared__ unsigned short wx2[32][256][8];    // Wx slice, interleaved: 131072 B
  __shared__ unsigned short hl[2][32][16][8];   // h tiles, interleaved:   16384 B

  // ---- preload Wx slice (block cols: gate*256 + cg*64 + dl) into wx2 ----
  const unsigned short* wxd = wxt + (size_t)d * 262144;
  for (int it = 0; it < 32; ++it) {
    int idx = it * 256 + tid;                 // 8192 16B-chunks
    int cl = idx & 255, ch = idx >> 8;        // cl = cs*64+dl, ch = kt*4+q
    int gcol = (cl >> 6) * 256 + cg * 64 + (cl & 63);
    *(short8*)(&wx2[ch][cl][0]) = *(const short8*)(wxd + (size_t)gcol * 256 + ch * 8);
  }

  // ---- Wh B-fragments resident in VGPRs/AGPRs (128 regs/lane) ----
  const unsigned short* whd = wht + (size_t)d * 262144;
  short8 bfr[4][8];
#pragma unroll
  for (int cs = 0; cs < 4; cs++) {
    const unsigned short* wp = whd + (size_t)(cs * 256 + cg * 64 + w * 16 + l16) * 256;
#pragma unroll
    for (int kt = 0; kt < 8; kt++)
      bfr[cs][kt] = *(const short8*)(wp + kt * 32 + q * 8);
  }

  // zero h LDS tiles (h0 = 0)
  {
    unsigned int* hlw = (unsigned int*)&hl[0][0][0][0];
    for (int i = tid; i < 4096; i += 256) hlw[i] = 0;
  }
  __syncthreads();

  const float* bias = d ? bb_ : bf_;
  float bv[4];
#pragma unroll
  for (int cs = 0; cs < 4; cs++) bv[cs] = bias[cs * 256 + cg * 64 + w * 16 + l16];

  float cst[4] = {0.f, 0.f, 0.f, 0.f};        // c for (row=q*4+r, dim=w*16+l16)
  unsigned int* hb = hbufw + (size_t)gid * 8192;            // primary, per group
  int prow = w * 4 + (lane >> 4);             // this wave's poll rows: 4w..4w+3
  int ps   = lane & 15;                        // dim quad within 64
  int rcg0 = (cg + 1) & 3, rcg1 = (cg + 2) & 3, rcg2 = (cg + 3) & 3;
  int pbase = prow * 256 + ps * 4;            // words
  int srow  = (q * 4) * 256 + cg * 64 + w * 16 + l16;       // producer base
  const int* tokrow = tokens + (rg * 16 + l16) * 512;

  int limit = 16;                              // adaptive sc0 poll budget

  // prologue: emb row for t=0
  short8 ea[8];
  {
    int ts0 = d ? 511 : 0;
    int tok0 = tokrow[ts0];
    const unsigned short* er = embbf + (size_t)tok0 * 256 + q * 8;
#pragma unroll
    for (int kt = 0; kt < 8; ++kt) ea[kt] = *(const short8*)(er + kt * 32);
  }

  for (int t = 0; t < 512; ++t) {
    int buf = t & 1;
    int tsn = (t < 511) ? (d ? 510 - t : t + 1) : 0;   // next-step token col
    int tok_n = tokrow[tsn];

    // ---- zx tile MFMA (uses prefetched ea; h-independent; overlaps the
    //      propagation of our un-drained stores from the previous step) ----
    f32x4 acc[4];
#pragma unroll
    for (int cs = 0; cs < 4; ++cs) acc[cs] = {0.f, 0.f, 0.f, 0.f};
#pragma unroll
    for (int kt = 0; kt < 8; ++kt) {
#pragma unroll
      for (int cs = 0; cs < 4; ++cs) {
        short8 xb = *(const short8*)(&wx2[kt * 4 + q][cs * 64 + w * 16 + l16][0]);
        acc[cs] = __builtin_amdgcn_mfma_f32_16x16x32_bf16(ea[kt], xb, acc[cs], 0, 0, 0);
      }
    }

    // ---- poll: this wave's 4 rows x 3 remote producers.
    // Phase 1: sc0 primary (fast iff group co-resident on one XCD), up to
    // `limit` rounds. Phase 2 (guaranteed): sc1 mirror — always written by
    // producers, correct under any placement. First round's vmcnt(0) also
    // drains our 8 un-drained stores from the previous step.
    const unsigned int* q0 = hb + buf * 4096 + pbase + rcg0 * 64;
    const unsigned int* q1 = hb + buf * 4096 + pbase + rcg1 * 64;
    const unsigned int* q2 = hb + buf * 4096 + pbase + rcg2 * 64;
    unsigned int tg = (unsigned int)t << 16;
    uint4v r0, r1, r2;
    bool got = false;
    for (int it = 0; it < limit; ++it) {
      asm volatile(
          "global_load_dwordx4 %[r0], %[p0], off sc0\n\t"
          "global_load_dwordx4 %[r1], %[p1], off sc0\n\t"
          "global_load_dwordx4 %[r2], %[p2], off sc0\n\t"
          "s_waitcnt vmcnt(0)"
          : [r0] "=&v"(r0), [r1] "=&v"(r1), [r2] "=&v"(r2)
          : [p0] "v"(q0), [p1] "v"(q1), [p2] "v"(q2)
          : "memory");
      unsigned int bad = (r0[0] ^ tg) | (r0[1] ^ tg) | (r0[2] ^ tg) | (r0[3] ^ tg)
                       | (r1[0] ^ tg) | (r1[1] ^ tg) | (r1[2] ^ tg) | (r1[3] ^ tg)
                       | (r2[0] ^ tg) | (r2[1] ^ tg) | (r2[2] ^ tg) | (r2[3] ^ tg);
      if (__all((bad & 0xffff0000u) == 0)) { got = true; break; }
    }
    if (!got) {
      limit >>= 1;                             // sticky decay toward sc1-only
      const unsigned int* m0 = q0 + 65536;
      const unsigned int* m1 = q1 + 65536;
      const unsigned int* m2 = q2 + 65536;
      while (true) {
        asm volatile(
            "global_load_dwordx4 %[r0], %[p0], off sc1\n\t"
            "global_load_dwordx4 %[r1], %[p1], off sc1\n\t"
            "global_load_dwordx4 %[r2], %[p2], off sc1\n\t"
            "s_waitcnt vmcnt(0)"
            : [r0] "=&v"(r0), [r1] "=&v"(r1), [r2] "=&v"(r2)
            : [p0] "v"(m0), [p1] "v"(m1), [p2] "v"(m2)
            : "memory");
        unsigned int bad = (r0[0] ^ tg) | (r0[1] ^ tg) | (r0[2] ^ tg) | (r0[3] ^ tg)
                         | (r1[0] ^ tg) | (r1[1] ^ tg) | (r1[2] ^ tg) | (r1[3] ^ tg)
                         | (r2[0] ^ tg) | (r2[1] ^ tg) | (r2[2] ^ tg) | (r2[3] ^ tg);
        if (__all((bad & 0xffff0000u) == 0)) break;
      }
    }

    // ---- emb prefetch for t+1 (flies during h-GEMM + epilogue) ----
    short8 ean[8];
    {
      const unsigned short* ern = embbf + (size_t)tok_n * 256 + q * 8;
#pragma unroll
      for (int kt = 0; kt < 8; ++kt) ean[kt] = *(const short8*)(ern + kt * 32);
    }

    // deposit packed bf16 into hl[buf] (remote dims; own dims already there)
    {
      int e4 = (ps & 1) * 4, ch2 = ps >> 1;
      uint2v w0, w1, w2;
      w0[0] = __builtin_amdgcn_perm(r0[1], r0[0], 0x05040100u);
      w0[1] = __builtin_amdgcn_perm(r0[3], r0[2], 0x05040100u);
      w1[0] = __builtin_amdgcn_perm(r1[1], r1[0], 0x05040100u);
      w1[1] = __builtin_amdgcn_perm(r1[3], r1[2], 0x05040100u);
      w2[0] = __builtin_amdgcn_perm(r2[1], r2[0], 0x05040100u);
      w2[1] = __builtin_amdgcn_perm(r2[3], r2[2], 0x05040100u);
      *(uint2v*)(&hl[buf][rcg0 * 8 + ch2][prow][e4]) = w0;
      *(uint2v*)(&hl[buf][rcg1 * 8 + ch2][prow][e4]) = w1;
      *(uint2v*)(&hl[buf][rcg2 * 8 + ch2][prow][e4]) = w2;
    }
    __syncthreads();   // hl[buf] complete; also publishes prev epilogue writes

    // ---- h GEMM: A from LDS tile (conflict-free b128), B from regs ----
#pragma unroll
    for (int kt = 0; kt < 8; ++kt) {
      short8 ha = *(const short8*)(&hl[buf][kt * 4 + q][l16][0]);
#pragma unroll
      for (int cs = 0; cs < 4; ++cs)
        acc[cs] = __builtin_amdgcn_mfma_f32_16x16x32_bf16(ha, bfr[cs][kt], acc[cs], 0, 0, 0);
    }

    // ---- epilogue: gates, c/h update, LDS own-dims, dual tagged stores ----
    unsigned int* hwn = hb + ((buf ^ 1) * 4096) + srow;
    unsigned int wtag = ((unsigned int)(t + 1)) << 16;
    int dim = cg * 64 + w * 16 + l16;
    int chO = dim >> 3, eO = dim & 7;
    unsigned int sw[4];
#pragma unroll
    for (int r = 0; r < 4; ++r) {
      float iv = sigf(acc[0][r] + bv[0]);
      float fv = sigf(acc[1][r] + bv[1]);
      float gv = tanhf_(acc[2][r] + bv[2]);
      float ov = sigf(acc[3][r] + bv[3]);
      cst[r] = fv * cst[r] + iv * gv;
      float hv = ov * tanhf_(cst[r]);
      unsigned short h16 = f2bf(hv);
      sw[r] = wtag | (unsigned int)h16;
      hl[buf ^ 1][chO][q * 4 + r][eO] = h16;
    }
    // dual-publish: sc0 primary (fast path) + sc1 mirror (guaranteed path).
    // NO drain: next poll's vmcnt(0) drains them, overlapped with zx MFMA.
    {
      unsigned int* hwm = hwn + 65536;
      asm volatile(
          "global_store_dword %[p], %[v0], off sc0\n\t"
          "global_store_dword %[p], %[v1], off offset:1024 sc0\n\t"
          "global_store_dword %[p], %[v2], off offset:2048 sc0\n\t"
          "global_store_dword %[p], %[v3], off offset:3072 sc0\n\t"
          "global_store_dword %[m], %[v0], off sc1\n\t"
          "global_store_dword %[m], %[v1], off offset:1024 sc1\n\t"
          "global_store_dword %[m], %[v2], off offset:2048 sc1\n\t"
          "global_store_dword %[m], %[v3], off offset:3072 sc1"
          :: [p] "v"(hwn), [m] "v"(hwm), [v0] "v"(sw[0]), [v1] "v"(sw[1]),
             [v2] "v"(sw[2]), [v3] "v"(sw[3])
          : "memory");
    }

    // rotate emb prefetch
#pragma unroll
    for (int kt = 0; kt < 8; ++kt) ea[kt] = ean[kt];
  }
}

// ---------------------------------------------------------------------------
// K3: logits + softmax. 64 blocks (one per batch) x 64 threads (one wave).
// Final h_512 sits in buf0 of each group's MIRROR (sc1-written; same
// cross-kernel coherence guarantees as the R5-proven path).
__global__ __launch_bounds__(64) void k3_out(
    const unsigned int* __restrict__ hbufw,
    const float* __restrict__ wout, const float* __restrict__ bout,
    float* __restrict__ out) {
  int b = blockIdx.x, tid = threadIdx.x;
  int rg = b >> 4, r = b & 15;
  const unsigned int* hf  = hbufw + 65536 + (size_t)rg * 8192 + r * 256;           // dir0
  const unsigned int* hbk = hbufw + 65536 + 32768 + (size_t)rg * 8192 + r * 256;   // dir1
  float p[10];
#pragma unroll
  for (int l = 0; l < 10; l++) p[l] = 0.f;
  for (int k = tid; k < 512; k += 64) {
    unsigned int wd = (k < 256) ? hf[k] : hbk[k - 256];
    float f = bf2f((unsigned short)(wd & 0xffffu));
    const float* wr = wout + k * 10;
#pragma unroll
    for (int l = 0; l < 10; l++) p[l] += f * wr[l];
  }
#pragma unroll
  for (int off = 32; off; off >>= 1)
#pragma unroll
    for (int l = 0; l < 10; l++) p[l] += __shfl_down(p[l], off);
  if (tid == 0) {
    float lg[10], m = -1e30f;
#pragma unroll
    for (int l = 0; l < 10; l++) { lg[l] = p[l] + bout[l]; m = fmaxf(m, lg[l]); }
    float sum = 0.f;
#pragma unroll
    for (int l = 0; l < 10; l++) { lg[l] = __expf(lg[l] - m); sum += lg[l]; }
    float inv = 1.0f / sum;
#pragma unroll
    for (int l = 0; l < 10; l++) out[b * 10 + l] = lg[l] * inv;
  }
}

// ---------------------------------------------------------------------------
extern "C" void kernel_launch(void* const* d_in, const int* in_sizes, int n_in,
                              void* d_out, int out_size, void* d_ws, size_t ws_size,
                              hipStream_t stream) {
  const int*   tokens = (const int*)d_in[0];
  const float* emb    = (const float*)d_in[1];
  const float* wxf    = (const float*)d_in[2];
  const float* whf    = (const float*)d_in[3];
  const float* bf_    = (const float*)d_in[4];
  const float* wxb    = (const float*)d_in[5];
  const float* whb    = (const float*)d_in[6];
  const float* bb_    = (const float*)d_in[7];
  const float* wout   = (const float*)d_in[8];
  const float* bout   = (const float*)d_in[9];
  float* out = (float*)d_out;

  char* ws = (char*)d_ws;
  unsigned short* embbf = (unsigned short*)(ws + EMB16_OFF);
  unsigned short* wxt   = (unsigned short*)(ws + WXT_OFF);
  unsigned short* wht   = (unsigned short*)(ws + WHT_OFF);
  unsigned int*   hbufw = (unsigned int*)(ws + HBUF_OFF);
  (void)ws_size; (void)in_sizes; (void)n_in; (void)out_size;   // needs WS_NEED bytes

  // zero h0 (tag 0 == step 0) in primary AND mirror buffers
  hipMemsetAsync(ws + HBUF_OFF, 0, 524288, stream);

  k0_transpose<<<dim3(8, 32, 4), 256, 0, stream>>>(wxf, wxb, whf, whb, wxt, wht);
  k0b_embcast<<<6250, 256, 0, stream>>>(emb, embbf);
  k2_rnn<<<32, 256, 0, stream>>>(tokens, embbf, wxt, wht, bf_, bb_, hbufw);
  k3_out<<<64, 64, 0, stream>>>(hbufw, wout, bout, out);
}